// Round 1
// baseline (3218.667 us; speedup 1.0000x reference)
//
#include <hip/hip_runtime.h>
#include <math.h>

#define N_NODES 40000
#define N_EDGES 640000
#define D       256
#define H       8
#define DH      32
#define DFF     1024
#define D3      768
#define ATT_SCALE 0.0625f   // 256^-0.5
#define LN_EPS  1e-5f

// ---------------------------------------------------------------------------
// LayerNorm: one 64-lane wave per row (D=256 -> float4 per lane).
// ---------------------------------------------------------------------------
__global__ __launch_bounds__(256) void ln_kernel(const float* __restrict__ in,
                                                 const float* __restrict__ g,
                                                 const float* __restrict__ b,
                                                 float* __restrict__ out)
{
    const int row  = blockIdx.x * 4 + (threadIdx.x >> 6);
    const int lane = threadIdx.x & 63;
    const float4 v = *reinterpret_cast<const float4*>(in + (size_t)row * D + lane * 4);
    float s  = v.x + v.y + v.z + v.w;
    float s2 = v.x * v.x + v.y * v.y + v.z * v.z + v.w * v.w;
#pragma unroll
    for (int o = 32; o > 0; o >>= 1) {
        s  += __shfl_xor(s,  o, 64);
        s2 += __shfl_xor(s2, o, 64);
    }
    const float mu  = s * (1.0f / D);
    const float var = s2 * (1.0f / D) - mu * mu;
    const float rs  = rsqrtf(var + LN_EPS);
    const float4 gg = *reinterpret_cast<const float4*>(g + lane * 4);
    const float4 bb = *reinterpret_cast<const float4*>(b + lane * 4);
    float4 o4;
    o4.x = (v.x - mu) * rs * gg.x + bb.x;
    o4.y = (v.y - mu) * rs * gg.y + bb.y;
    o4.z = (v.z - mu) * rs * gg.z + bb.z;
    o4.w = (v.w - mu) * rs * gg.w + bb.w;
    *reinterpret_cast<float4*>(out + (size_t)row * D + lane * 4) = o4;
}

// ---------------------------------------------------------------------------
// fp32 tiled GEMM: C[M,N] = A[M,K] @ B[K,N] + bias, with epilogue variants.
// BM=BN=64, BK=16, 256 threads, 4x4 micro-tile. M%64==0, N%64==0, K%16==0.
// EPI 0: scale cols < 256 by ATT_SCALE (qkv: q part)
// EPI 1: exact gelu
// EPI 2: += Xadd[r, c]   (final residual, C = d_out)
// ---------------------------------------------------------------------------
template <int EPI>
__global__ __launch_bounds__(256) void gemm_kernel(const float* __restrict__ A,
                                                   const float* __restrict__ B,
                                                   const float* __restrict__ bias,
                                                   float* __restrict__ C,
                                                   const float* __restrict__ Xadd,
                                                   int M, int N, int K)
{
    __shared__ float As[16][68];   // [k][m], stride 68 floats = 17x16B (aligned)
    __shared__ float Bs[16][68];   // [k][n]

    const int tid  = threadIdx.x;
    const int tx   = tid & 15;     // col group
    const int ty   = tid >> 4;     // row group
    const int row0 = blockIdx.y * 64;
    const int col0 = blockIdx.x * 64;

    float acc[4][4] = {};

    for (int k0 = 0; k0 < K; k0 += 16) {
        // A tile: 64 rows x 16 k ; thread loads one float4 along k
        {
            const int ar = tid >> 2;          // 0..63
            const int ak = (tid & 3) << 2;    // 0,4,8,12
            const float4 v = *reinterpret_cast<const float4*>(
                A + (size_t)(row0 + ar) * K + k0 + ak);
            As[ak + 0][ar] = v.x;
            As[ak + 1][ar] = v.y;
            As[ak + 2][ar] = v.z;
            As[ak + 3][ar] = v.w;
        }
        // B tile: 16 k x 64 cols ; thread loads one float4 along n
        {
            const int br = tid >> 4;          // 0..15
            const int bc = (tid & 15) << 2;   // 0..60
            const float4 v = *reinterpret_cast<const float4*>(
                B + (size_t)(k0 + br) * N + col0 + bc);
            *reinterpret_cast<float4*>(&Bs[br][bc]) = v;
        }
        __syncthreads();
#pragma unroll
        for (int k = 0; k < 16; ++k) {
            const float4 a = *reinterpret_cast<const float4*>(&As[k][ty * 4]);
            const float4 b = *reinterpret_cast<const float4*>(&Bs[k][tx * 4]);
            const float av[4] = {a.x, a.y, a.z, a.w};
            const float bv[4] = {b.x, b.y, b.z, b.w};
#pragma unroll
            for (int i = 0; i < 4; ++i)
#pragma unroll
                for (int j = 0; j < 4; ++j)
                    acc[i][j] += av[i] * bv[j];
        }
        __syncthreads();
    }

    const int cbase = col0 + tx * 4;
    const float4 bz = *reinterpret_cast<const float4*>(bias + cbase);
#pragma unroll
    for (int i = 0; i < 4; ++i) {
        const int r = row0 + ty * 4 + i;
        float4 o;
        o.x = acc[i][0] + bz.x;
        o.y = acc[i][1] + bz.y;
        o.z = acc[i][2] + bz.z;
        o.w = acc[i][3] + bz.w;
        if (EPI == 0) {
            if (cbase < 256) { o.x *= ATT_SCALE; o.y *= ATT_SCALE; o.z *= ATT_SCALE; o.w *= ATT_SCALE; }
        } else if (EPI == 1) {
            o.x = 0.5f * o.x * (1.0f + erff(o.x * 0.70710678118654752f));
            o.y = 0.5f * o.y * (1.0f + erff(o.y * 0.70710678118654752f));
            o.z = 0.5f * o.z * (1.0f + erff(o.z * 0.70710678118654752f));
            o.w = 0.5f * o.w * (1.0f + erff(o.w * 0.70710678118654752f));
        } else if (EPI == 2) {
            const float4 xa = *reinterpret_cast<const float4*>(Xadd + (size_t)r * N + cbase);
            o.x += xa.x; o.y += xa.y; o.z += xa.z; o.w += xa.w;
        }
        *reinterpret_cast<float4*>(C + (size_t)r * N + cbase) = o;
    }
}

// ---------------------------------------------------------------------------
// Edge scores: one wave per edge. Lane l covers qkv cols l*4..l*4+3.
// Head h owns lanes 8h..8h+7. e = exp(q.k)  (scores are tiny; max-sub is a
// mathematical no-op for the normalized weights). Segment-sum via atomics.
// ---------------------------------------------------------------------------
__global__ __launch_bounds__(256) void score_kernel(const float* __restrict__ qkv,
                                                    const int* __restrict__ src,
                                                    const int* __restrict__ dst,
                                                    float* __restrict__ esc,
                                                    float* __restrict__ ssum)
{
    const int e    = blockIdx.x * 4 + (threadIdx.x >> 6);
    const int lane = threadIdx.x & 63;
    const int se = src[e];
    const int de = dst[e];
    const float4 q = *reinterpret_cast<const float4*>(qkv + (size_t)se * D3 + lane * 4);
    const float4 k = *reinterpret_cast<const float4*>(qkv + (size_t)de * D3 + 256 + lane * 4);
    float p = q.x * k.x + q.y * k.y + q.z * k.z + q.w * k.w;
    p += __shfl_xor(p, 1, 64);
    p += __shfl_xor(p, 2, 64);
    p += __shfl_xor(p, 4, 64);
    if ((lane & 7) == 0) {
        const int h = lane >> 3;
        const float ex = expf(p);
        esc[(size_t)e * H + h] = ex;
        atomicAdd(&ssum[(size_t)de * H + h], ex);
    }
}

// ---------------------------------------------------------------------------
// Aggregation: one wave per edge; lane l handles 4 consecutive dims (same
// head). x (pre-seeded with triplet_h) += v[src] * softmax_weight, atomics.
// ---------------------------------------------------------------------------
__global__ __launch_bounds__(256) void agg_kernel(const float* __restrict__ qkv,
                                                  const int* __restrict__ src,
                                                  const int* __restrict__ dst,
                                                  const float* __restrict__ esc,
                                                  const float* __restrict__ ssum,
                                                  float* __restrict__ x)
{
    const int e    = blockIdx.x * 4 + (threadIdx.x >> 6);
    const int lane = threadIdx.x & 63;
    const int se = src[e];
    const int de = dst[e];
    const int h  = lane >> 3;
    const float sa = esc[(size_t)e * H + h] / ssum[(size_t)de * H + h];
    const float4 v = *reinterpret_cast<const float4*>(qkv + (size_t)se * D3 + 512 + lane * 4);
    float* xp = x + (size_t)de * D + lane * 4;
    atomicAdd(xp + 0, v.x * sa);
    atomicAdd(xp + 1, v.y * sa);
    atomicAdd(xp + 2, v.z * sa);
    atomicAdd(xp + 3, v.w * sa);
}

// ---------------------------------------------------------------------------
extern "C" void kernel_launch(void* const* d_in, const int* in_sizes, int n_in,
                              void* d_out, int out_size, void* d_ws, size_t ws_size,
                              hipStream_t stream)
{
    const float* triplet_h = (const float*)d_in[0];
    const int*   src       = (const int*)d_in[1];
    const int*   dst       = (const int*)d_in[2];
    const float* Wqkv      = (const float*)d_in[3];
    const float* bqkv      = (const float*)d_in[4];
    const float* ln_attn_g = (const float*)d_in[5];
    const float* ln_attn_b = (const float*)d_in[6];
    const float* ln_res_g  = (const float*)d_in[7];
    const float* ln_res_b  = (const float*)d_in[8];
    const float* W_in      = (const float*)d_in[9];
    const float* b_in      = (const float*)d_in[10];
    const float* W_out     = (const float*)d_in[11];
    const float* b_out     = (const float*)d_in[12];
    float* out = (float*)d_out;

    // Workspace layout (lifetimes overlap-checked):
    //   qkv_a1 : N*DFF floats  -- qkv (N*768) during attention, a1 (N*1024) in FFN
    //   h_xn   : N*D           -- h (LN1 out) then xn (LN2 out)
    //   x      : N*D           -- triplet_h + agg (residual carrier)
    //   esc    : E*H           -- exp(scores)
    //   ssum   : N*H           -- softmax denominators
    char* w = (char*)d_ws;
    float* qkv_a1 = (float*)w;  w += (size_t)N_NODES * DFF * sizeof(float);
    float* h_xn   = (float*)w;  w += (size_t)N_NODES * D   * sizeof(float);
    float* x      = (float*)w;  w += (size_t)N_NODES * D   * sizeof(float);
    float* esc    = (float*)w;  w += (size_t)N_EDGES * H   * sizeof(float);
    float* ssum   = (float*)w;  w += (size_t)N_NODES * H   * sizeof(float);

    hipMemsetAsync(ssum, 0, (size_t)N_NODES * H * sizeof(float), stream);
    hipMemcpyAsync(x, triplet_h, (size_t)N_NODES * D * sizeof(float),
                   hipMemcpyDeviceToDevice, stream);

    // 1) h = LN(triplet_h)
    ln_kernel<<<N_NODES / 4, 256, 0, stream>>>(triplet_h, ln_attn_g, ln_attn_b, h_xn);
    // 2) qkv = h @ Wqkv + bqkv  (q part scaled)
    gemm_kernel<0><<<dim3(D3 / 64, N_NODES / 64), 256, 0, stream>>>(
        h_xn, Wqkv, bqkv, qkv_a1, nullptr, N_NODES, D3, D);
    // 3) edge scores -> exp -> segment sums
    score_kernel<<<N_EDGES / 4, 256, 0, stream>>>(qkv_a1, src, dst, esc, ssum);
    // 4) x = triplet_h + segment_sum(v[src] * softmax)
    agg_kernel<<<N_EDGES / 4, 256, 0, stream>>>(qkv_a1, src, dst, esc, ssum, x);
    // 5) xn = LN(x)
    ln_kernel<<<N_NODES / 4, 256, 0, stream>>>(x, ln_res_g, ln_res_b, h_xn);
    // 6) a1 = gelu(xn @ W_in + b_in)
    gemm_kernel<1><<<dim3(DFF / 64, N_NODES / 64), 256, 0, stream>>>(
        h_xn, W_in, b_in, qkv_a1, nullptr, N_NODES, DFF, D);
    // 7) out = x + a1 @ W_out + b_out
    gemm_kernel<2><<<dim3(D / 64, N_NODES / 64), 256, 0, stream>>>(
        qkv_a1, W_out, b_out, out, x, N_NODES, D, DFF);

    (void)in_sizes; (void)n_in; (void)out_size; (void)ws_size;
}

// Round 3
// 1419.986 us; speedup vs baseline: 2.2667x; 2.2667x over previous
//
#include <hip/hip_runtime.h>
#include <math.h>

#define N_NODES 40000
#define N_EDGES 640000
#define D       256
#define H       8
#define DH      32
#define DFF     1024
#define D3      768
#define ATT_SCALE 0.0625f   // 256^-0.5
#define LN_EPS  1e-5f

// ---------------------------------------------------------------------------
// LayerNorm: one 64-lane wave per row (D=256 -> float4 per lane).
// ---------------------------------------------------------------------------
__global__ __launch_bounds__(256) void ln_kernel(const float* __restrict__ in,
                                                 const float* __restrict__ g,
                                                 const float* __restrict__ b,
                                                 float* __restrict__ out)
{
    const int row  = blockIdx.x * 4 + (threadIdx.x >> 6);
    const int lane = threadIdx.x & 63;
    const float4 v = *reinterpret_cast<const float4*>(in + (size_t)row * D + lane * 4);
    float s  = v.x + v.y + v.z + v.w;
    float s2 = v.x * v.x + v.y * v.y + v.z * v.z + v.w * v.w;
#pragma unroll
    for (int o = 32; o > 0; o >>= 1) {
        s  += __shfl_xor(s,  o, 64);
        s2 += __shfl_xor(s2, o, 64);
    }
    const float mu  = s * (1.0f / D);
    const float var = s2 * (1.0f / D) - mu * mu;
    const float rs  = rsqrtf(var + LN_EPS);
    const float4 gg = *reinterpret_cast<const float4*>(g + lane * 4);
    const float4 bb = *reinterpret_cast<const float4*>(b + lane * 4);
    float4 o4;
    o4.x = (v.x - mu) * rs * gg.x + bb.x;
    o4.y = (v.y - mu) * rs * gg.y + bb.y;
    o4.z = (v.z - mu) * rs * gg.z + bb.z;
    o4.w = (v.w - mu) * rs * gg.w + bb.w;
    *reinterpret_cast<float4*>(out + (size_t)row * D + lane * 4) = o4;
}

// ---------------------------------------------------------------------------
// fp32 tiled GEMM: C[M,N] = A[M,K] @ B[K,N] + bias, with epilogue variants.
// BM=BN=64, BK=16, 256 threads, 4x4 micro-tile.
// EPI 0: scale cols < 256 by ATT_SCALE   EPI 1: exact gelu   EPI 2: += Xadd
// ---------------------------------------------------------------------------
template <int EPI>
__global__ __launch_bounds__(256) void gemm_kernel(const float* __restrict__ A,
                                                   const float* __restrict__ B,
                                                   const float* __restrict__ bias,
                                                   float* __restrict__ C,
                                                   const float* __restrict__ Xadd,
                                                   int M, int N, int K)
{
    __shared__ float As[16][68];
    __shared__ float Bs[16][68];

    const int tid  = threadIdx.x;
    const int tx   = tid & 15;
    const int ty   = tid >> 4;
    const int row0 = blockIdx.y * 64;
    const int col0 = blockIdx.x * 64;

    float acc[4][4] = {};

    for (int k0 = 0; k0 < K; k0 += 16) {
        {
            const int ar = tid >> 2;
            const int ak = (tid & 3) << 2;
            const float4 v = *reinterpret_cast<const float4*>(
                A + (size_t)(row0 + ar) * K + k0 + ak);
            As[ak + 0][ar] = v.x;
            As[ak + 1][ar] = v.y;
            As[ak + 2][ar] = v.z;
            As[ak + 3][ar] = v.w;
        }
        {
            const int br = tid >> 4;
            const int bc = (tid & 15) << 2;
            const float4 v = *reinterpret_cast<const float4*>(
                B + (size_t)(k0 + br) * N + col0 + bc);
            *reinterpret_cast<float4*>(&Bs[br][bc]) = v;
        }
        __syncthreads();
#pragma unroll
        for (int k = 0; k < 16; ++k) {
            const float4 a = *reinterpret_cast<const float4*>(&As[k][ty * 4]);
            const float4 b = *reinterpret_cast<const float4*>(&Bs[k][tx * 4]);
            const float av[4] = {a.x, a.y, a.z, a.w};
            const float bv[4] = {b.x, b.y, b.z, b.w};
#pragma unroll
            for (int i = 0; i < 4; ++i)
#pragma unroll
                for (int j = 0; j < 4; ++j)
                    acc[i][j] += av[i] * bv[j];
        }
        __syncthreads();
    }

    const int cbase = col0 + tx * 4;
    const float4 bz = *reinterpret_cast<const float4*>(bias + cbase);
#pragma unroll
    for (int i = 0; i < 4; ++i) {
        const int r = row0 + ty * 4 + i;
        float4 o;
        o.x = acc[i][0] + bz.x;
        o.y = acc[i][1] + bz.y;
        o.z = acc[i][2] + bz.z;
        o.w = acc[i][3] + bz.w;
        if (EPI == 0) {
            if (cbase < 256) { o.x *= ATT_SCALE; o.y *= ATT_SCALE; o.z *= ATT_SCALE; o.w *= ATT_SCALE; }
        } else if (EPI == 1) {
            o.x = 0.5f * o.x * (1.0f + erff(o.x * 0.70710678118654752f));
            o.y = 0.5f * o.y * (1.0f + erff(o.y * 0.70710678118654752f));
            o.z = 0.5f * o.z * (1.0f + erff(o.z * 0.70710678118654752f));
            o.w = 0.5f * o.w * (1.0f + erff(o.w * 0.70710678118654752f));
        } else if (EPI == 2) {
            const float4 xa = *reinterpret_cast<const float4*>(Xadd + (size_t)r * N + cbase);
            o.x += xa.x; o.y += xa.y; o.z += xa.z; o.w += xa.w;
        }
        *reinterpret_cast<float4*>(C + (size_t)r * N + cbase) = o;
    }
}

// ---------------------------------------------------------------------------
// Edge scores: one wave per edge. Writes exp(q.k) per (edge, head). No atomics.
// ---------------------------------------------------------------------------
__global__ __launch_bounds__(256) void score_kernel(const float* __restrict__ qkv,
                                                    const int* __restrict__ src,
                                                    const int* __restrict__ dst,
                                                    float* __restrict__ esc)
{
    const int e    = blockIdx.x * 4 + (threadIdx.x >> 6);
    const int lane = threadIdx.x & 63;
    const int se = src[e];
    const int de = dst[e];
    const float4 q = *reinterpret_cast<const float4*>(qkv + (size_t)se * D3 + lane * 4);
    const float4 k = *reinterpret_cast<const float4*>(qkv + (size_t)de * D3 + 256 + lane * 4);
    float p = q.x * k.x + q.y * k.y + q.z * k.z + q.w * k.w;
    p += __shfl_xor(p, 1, 64);
    p += __shfl_xor(p, 2, 64);
    p += __shfl_xor(p, 4, 64);
    if ((lane & 7) == 0) {
        esc[(size_t)e * H + (lane >> 3)] = expf(p);
    }
}

// ---------------------------------------------------------------------------
// CSR build: histogram -> chunked single-block scan (256 thr) -> fill
// ---------------------------------------------------------------------------
__global__ __launch_bounds__(256) void hist_kernel(const int* __restrict__ dst,
                                                   int* __restrict__ counts)
{
    const int i = blockIdx.x * 256 + threadIdx.x;
    atomicAdd(&counts[dst[i]], 1);
}

__global__ __launch_bounds__(256) void scan_kernel(const int* __restrict__ counts,
                                                   int* __restrict__ rowptr)
{
    const int PER = (N_NODES + 255) / 256;     // 157
    const int tid = threadIdx.x;
    const int base = tid * PER;
    int s = 0;
    for (int i = 0; i < PER; ++i) {
        const int idx = base + i;
        if (idx < N_NODES) s += counts[idx];
    }
    __shared__ int sm[256];
    sm[tid] = s;
    __syncthreads();
    for (int off = 1; off < 256; off <<= 1) {
        int t = (tid >= off) ? sm[tid - off] : 0;
        __syncthreads();
        sm[tid] += t;
        __syncthreads();
    }
    const int incl = sm[tid];
    int run = incl - s;                        // exclusive base for this chunk
    for (int i = 0; i < PER; ++i) {
        const int idx = base + i;
        if (idx < N_NODES) {
            rowptr[idx] = run;
            run += counts[idx];
        }
    }
    if (tid == 255) rowptr[N_NODES] = incl;    // total = N_EDGES
}

__global__ __launch_bounds__(256) void fill_kernel(const int* __restrict__ dst,
                                                   int* __restrict__ cursor,
                                                   int* __restrict__ eids)
{
    const int e = blockIdx.x * 256 + threadIdx.x;
    const int pos = atomicAdd(&cursor[dst[e]], 1);
    if (pos >= 0 && pos < N_EDGES) eids[pos] = e;   // defensive: fault -> wrong-answer
}

// ---------------------------------------------------------------------------
// Gather aggregation: one wave per dst node. Pass 1: softmax denom per head
// (registers). Pass 2: acc += v[src] * w. Writes x = triplet_h + agg once.
// No atomics anywhere.
// ---------------------------------------------------------------------------
__global__ __launch_bounds__(256) void gather_kernel(const float* __restrict__ qkv,
                                                     const float* __restrict__ esc,
                                                     const int* __restrict__ src,
                                                     const int* __restrict__ rowptr,
                                                     const int* __restrict__ eids,
                                                     const float* __restrict__ triplet_h,
                                                     float* __restrict__ x)
{
    const int node = blockIdx.x * 4 + (threadIdx.x >> 6);
    const int lane = threadIdx.x & 63;
    const int h    = lane >> 3;                 // head owning these 4 dims
    int beg = rowptr[node];
    int end = rowptr[node + 1];
    beg = max(0, min(beg, N_EDGES));            // defensive clamps
    end = max(beg, min(end, N_EDGES));

    float dsum = 0.0f;
    for (int j = beg; j < end; ++j) {
        const int e = eids[j];
        dsum += esc[(size_t)e * H + h];
    }
    const float inv = 1.0f / dsum;              // unused if end==beg

    float4 acc = {0.0f, 0.0f, 0.0f, 0.0f};
    for (int j = beg; j < end; ++j) {
        const int e  = eids[j];
        const int se = src[e];
        const float w = esc[(size_t)e * H + h] * inv;
        const float4 v = *reinterpret_cast<const float4*>(
            qkv + (size_t)se * D3 + 512 + lane * 4);
        acc.x += v.x * w;
        acc.y += v.y * w;
        acc.z += v.z * w;
        acc.w += v.w * w;
    }
    const float4 th = *reinterpret_cast<const float4*>(
        triplet_h + (size_t)node * D + lane * 4);
    float4 o;
    o.x = th.x + acc.x;
    o.y = th.y + acc.y;
    o.z = th.z + acc.z;
    o.w = th.w + acc.w;
    *reinterpret_cast<float4*>(x + (size_t)node * D + lane * 4) = o;
}

// ---------------------------------------------------------------------------
extern "C" void kernel_launch(void* const* d_in, const int* in_sizes, int n_in,
                              void* d_out, int out_size, void* d_ws, size_t ws_size,
                              hipStream_t stream)
{
    const float* triplet_h = (const float*)d_in[0];
    const int*   src       = (const int*)d_in[1];
    const int*   dst       = (const int*)d_in[2];
    const float* Wqkv      = (const float*)d_in[3];
    const float* bqkv      = (const float*)d_in[4];
    const float* ln_attn_g = (const float*)d_in[5];
    const float* ln_attn_b = (const float*)d_in[6];
    const float* ln_res_g  = (const float*)d_in[7];
    const float* ln_res_b  = (const float*)d_in[8];
    const float* W_in      = (const float*)d_in[9];
    const float* b_in      = (const float*)d_in[10];
    const float* W_out     = (const float*)d_in[11];
    const float* b_out     = (const float*)d_in[12];
    float* out = (float*)d_out;

    // Workspace layout (245.76 MB total; R1's 267.5 MB is the proven ceiling):
    //   bufA : N*DFF floats (163.84 MB)
    //          - first N*768 floats: qkv   (live LN1 -> gather)
    //          - as N*1024 floats:   a1    (live FFN only, after gather)
    //          - tail 40.96 MB (bytes N*768*4 .. N*1024*4): esc + CSR arrays,
    //            all dead before a1 is written.
    //   h_xn : N*D (h then xn)
    //   x    : N*D (residual carrier)
    char* w = (char*)d_ws;
    float* bufA = (float*)w;  w += (size_t)N_NODES * DFF * sizeof(float);
    float* h_xn = (float*)w;  w += (size_t)N_NODES * D   * sizeof(float);
    float* x    = (float*)w;  w += (size_t)N_NODES * D   * sizeof(float);

    float* qkv = bufA;
    float* a1  = bufA;
    char* t = (char*)bufA + (size_t)N_NODES * D3 * sizeof(float);  // 40.96 MB tail
    float* esc    = (float*)t;  t += (size_t)N_EDGES * H   * sizeof(float); // 20.48 MB
    int*   counts = (int*)t;    t += (size_t)N_NODES       * sizeof(int);
    int*   rowptr = (int*)t;    t += (size_t)(N_NODES + 1) * sizeof(int);
    int*   cursor = (int*)t;    t += (size_t)N_NODES       * sizeof(int);
    int*   eids   = (int*)t;    t += (size_t)N_EDGES       * sizeof(int);   // 2.56 MB

    // ---- CSR build (depends only on dst) ----
    hipMemsetAsync(counts, 0, (size_t)N_NODES * sizeof(int), stream);
    hist_kernel<<<N_EDGES / 256, 256, 0, stream>>>(dst, counts);
    scan_kernel<<<1, 256, 0, stream>>>(counts, rowptr);
    hipMemcpyAsync(cursor, rowptr, (size_t)N_NODES * sizeof(int),
                   hipMemcpyDeviceToDevice, stream);
    fill_kernel<<<N_EDGES / 256, 256, 0, stream>>>(dst, cursor, eids);

    // ---- main pipeline ----
    ln_kernel<<<N_NODES / 4, 256, 0, stream>>>(triplet_h, ln_attn_g, ln_attn_b, h_xn);
    gemm_kernel<0><<<dim3(D3 / 64, N_NODES / 64), 256, 0, stream>>>(
        h_xn, Wqkv, bqkv, qkv, nullptr, N_NODES, D3, D);
    score_kernel<<<N_EDGES / 4, 256, 0, stream>>>(qkv, src, dst, esc);
    gather_kernel<<<N_NODES / 4, 256, 0, stream>>>(qkv, esc, src, rowptr, eids,
                                                   triplet_h, x);
    ln_kernel<<<N_NODES / 4, 256, 0, stream>>>(x, ln_res_g, ln_res_b, h_xn);
    // qkv/esc/CSR all dead from here; a1 may overwrite bufA.
    gemm_kernel<1><<<dim3(DFF / 64, N_NODES / 64), 256, 0, stream>>>(
        h_xn, W_in, b_in, a1, nullptr, N_NODES, DFF, D);
    gemm_kernel<2><<<dim3(D / 64, N_NODES / 64), 256, 0, stream>>>(
        a1, W_out, b_out, out, x, N_NODES, D, DFF);

    (void)in_sizes; (void)n_in; (void)out_size; (void)ws_size;
}

// Round 4
// 838.711 us; speedup vs baseline: 3.8376x; 1.6931x over previous
//
#include <hip/hip_runtime.h>
#include <math.h>

#define N_NODES 40000
#define M_PAD   40064      // 313 * 128
#define N_EDGES 640000
#define D       256
#define H       8
#define DFF     1024
#define D3      768
#define ATT_SCALE 0.0625f  // 256^-0.5
#define LN_EPS  1e-5f

typedef __attribute__((ext_vector_type(8))) short short8;
typedef __attribute__((ext_vector_type(4))) float f32x4;

__device__ __forceinline__ unsigned short f2bf(float f) {
    unsigned int u = __builtin_bit_cast(unsigned int, f);
    u = (u + 0x7FFF + ((u >> 16) & 1)) >> 16;   // RTNE
    return (unsigned short)u;
}

// ---------------------------------------------------------------------------
// LayerNorm -> bf16 row-major output. One wave per row.
// ---------------------------------------------------------------------------
__global__ __launch_bounds__(256) void ln_bf_kernel(const float* __restrict__ in,
                                                    const float* __restrict__ g,
                                                    const float* __restrict__ b,
                                                    unsigned short* __restrict__ out)
{
    const int row  = blockIdx.x * 4 + (threadIdx.x >> 6);
    const int lane = threadIdx.x & 63;
    const float4 v = *reinterpret_cast<const float4*>(in + (size_t)row * D + lane * 4);
    float s  = v.x + v.y + v.z + v.w;
    float s2 = v.x * v.x + v.y * v.y + v.z * v.z + v.w * v.w;
#pragma unroll
    for (int o = 32; o > 0; o >>= 1) {
        s  += __shfl_xor(s,  o, 64);
        s2 += __shfl_xor(s2, o, 64);
    }
    const float mu  = s * (1.0f / D);
    const float var = s2 * (1.0f / D) - mu * mu;
    const float rs  = rsqrtf(var + LN_EPS);
    const float4 gg = *reinterpret_cast<const float4*>(g + lane * 4);
    const float4 bb = *reinterpret_cast<const float4*>(b + lane * 4);
    ushort4 o4;
    o4.x = f2bf((v.x - mu) * rs * gg.x + bb.x);
    o4.y = f2bf((v.y - mu) * rs * gg.y + bb.y);
    o4.z = f2bf((v.z - mu) * rs * gg.z + bb.z);
    o4.w = f2bf((v.w - mu) * rs * gg.w + bb.w);
    *reinterpret_cast<ushort4*>(out + (size_t)row * D + lane * 4) = o4;
}

// ---------------------------------------------------------------------------
// Weight pack: W[K][N] fp32 -> bf16 packed [N/16][K/8][16][8].
// Thread handles one (ntile, kchunk, ni): reads 8 strided fp32, writes 16B.
// ---------------------------------------------------------------------------
template <int K, int N>
__global__ __launch_bounds__(256) void pack_w_kernel(const float* __restrict__ W,
                                                     unsigned short* __restrict__ Wpk)
{
    const int idx = blockIdx.x * 256 + threadIdx.x;   // [N/16][K/8][16]
    const int ni  = idx & 15;
    const int kc  = (idx >> 4) % (K / 8);
    const int nt  = idx / (16 * (K / 8));
    const int n   = nt * 16 + ni;
    unsigned short o[8];
#pragma unroll
    for (int i = 0; i < 8; ++i)
        o[i] = f2bf(W[(size_t)(kc * 8 + i) * N + n]);
    *reinterpret_cast<short8*>(Wpk + (size_t)idx * 8) = *reinterpret_cast<short8*>(o);
}

// ---------------------------------------------------------------------------
// bf16 MFMA GEMM: C[M,N] = A[Mpad,K]bf16 @ Bpk + bias.
// Block 256 thr = 4 waves; 128x128 tile; BK=32; wave -> 64x64 (4x4 mfma tiles).
// A staged row-major->fragment order on the fly; Bpk already fragment order.
// EPI 0: fp32 C, scale cols<256 by ATT_SCALE (qkv)
// EPI 1: bf16 C with exact gelu (a1)
// EPI 2: fp32 C += Xadd (final residual)
// ---------------------------------------------------------------------------
template <int EPI, int K, int N>
__global__ __launch_bounds__(256) void mfma_gemm_kernel(const unsigned short* __restrict__ A,
                                                        const unsigned short* __restrict__ Bpk,
                                                        const float* __restrict__ bias,
                                                        void* __restrict__ Cout,
                                                        const float* __restrict__ Xadd)
{
    __shared__ unsigned short As[4096];   // [mt8][kc4][mi16][ki8] = 8 KB
    __shared__ unsigned short Bs[4096];   // [nt8][kc4][ni16][ki8] = 8 KB

    const int tid  = threadIdx.x;
    const int wave = tid >> 6;
    const int lane = tid & 63;
    const int row0 = blockIdx.y * 128;
    const int col0 = blockIdx.x * 128;
    const int wm   = (wave >> 1) * 64;    // wave row offset in tile
    const int wn   = (wave & 1) * 64;     // wave col offset in tile

    f32x4 acc[4][4] = {};

    const int lq  = (lane >> 4);          // k-chunk of this lane's fragment
    const int lm  = (lane & 15);
    const int fragoff = lq * 128 + lm * 8;  // elements, within [kc][i16][8]

    for (int k0 = 0; k0 < K; k0 += 32) {
        // ---- stage A: q = p*256+tid ; c=q&3, mi=(q>>2)&15, mt=q>>6 ----
#pragma unroll
        for (int p = 0; p < 2; ++p) {
            const int q  = p * 256 + tid;
            const int c  = q & 3;
            const int mi = (q >> 2) & 15;
            const int mt = q >> 6;
            const short8 v = *reinterpret_cast<const short8*>(
                A + (size_t)(row0 + mt * 16 + mi) * K + k0 + c * 8);
            *reinterpret_cast<short8*>(&As[mt * 512 + c * 128 + mi * 8]) = v;
        }
        // ---- stage B: contiguous copy from packed global ----
#pragma unroll
        for (int p = 0; p < 2; ++p) {
            const int q   = p * 256 + tid;
            const int nt  = q >> 6;
            const int rem = q & 63;
            const short8 v = *reinterpret_cast<const short8*>(
                Bpk + ((size_t)(col0 / 16 + nt) * (K / 8) + k0 / 8) * 128 + rem * 8);
            *reinterpret_cast<short8*>(&Bs[q * 8]) = v;
        }
        __syncthreads();

        short8 af[4], bf[4];
#pragma unroll
        for (int i = 0; i < 4; ++i) {
            af[i] = *reinterpret_cast<const short8*>(&As[(wm / 16 + i) * 512 + fragoff]);
            bf[i] = *reinterpret_cast<const short8*>(&Bs[(wn / 16 + i) * 512 + fragoff]);
        }
#pragma unroll
        for (int i = 0; i < 4; ++i)
#pragma unroll
            for (int j = 0; j < 4; ++j)
                acc[i][j] = __builtin_amdgcn_mfma_f32_16x16x32_bf16(af[i], bf[j], acc[i][j], 0, 0, 0);
        __syncthreads();
    }

    // ---- epilogue: C/D layout col=lane&15, row=(lane>>4)*4+t ----
#pragma unroll
    for (int j = 0; j < 4; ++j) {
        const int col = col0 + wn + j * 16 + (lane & 15);
        const float bz = bias[col];
#pragma unroll
        for (int i = 0; i < 4; ++i) {
#pragma unroll
            for (int t = 0; t < 4; ++t) {
                const int r = row0 + wm + i * 16 + (lane >> 4) * 4 + t;
                if (r < N_NODES) {
                    float o = acc[i][j][t] + bz;
                    if (EPI == 0) {
                        if (col < 256) o *= ATT_SCALE;
                        ((float*)Cout)[(size_t)r * N + col] = o;
                    } else if (EPI == 1) {
                        o = 0.5f * o * (1.0f + erff(o * 0.70710678118654752f));
                        ((unsigned short*)Cout)[(size_t)r * N + col] = f2bf(o);
                    } else {
                        o += Xadd[(size_t)r * N + col];
                        ((float*)Cout)[(size_t)r * N + col] = o;
                    }
                }
            }
        }
    }
}

// ---------------------------------------------------------------------------
// Edge scores: one wave per edge. Writes exp(q.k) per (edge, head).
// ---------------------------------------------------------------------------
__global__ __launch_bounds__(256) void score_kernel(const float* __restrict__ qkv,
                                                    const int* __restrict__ src,
                                                    const int* __restrict__ dst,
                                                    float* __restrict__ esc)
{
    const int e    = blockIdx.x * 4 + (threadIdx.x >> 6);
    const int lane = threadIdx.x & 63;
    const int se = src[e];
    const int de = dst[e];
    const float4 q = *reinterpret_cast<const float4*>(qkv + (size_t)se * D3 + lane * 4);
    const float4 k = *reinterpret_cast<const float4*>(qkv + (size_t)de * D3 + 256 + lane * 4);
    float p = q.x * k.x + q.y * k.y + q.z * k.z + q.w * k.w;
    p += __shfl_xor(p, 1, 64);
    p += __shfl_xor(p, 2, 64);
    p += __shfl_xor(p, 4, 64);
    if ((lane & 7) == 0) {
        esc[(size_t)e * H + (lane >> 3)] = expf(p);
    }
}

// ---------------------------------------------------------------------------
// CSR build: histogram -> chunked single-block scan (256 thr) -> fill
// ---------------------------------------------------------------------------
__global__ __launch_bounds__(256) void hist_kernel(const int* __restrict__ dst,
                                                   int* __restrict__ counts)
{
    const int i = blockIdx.x * 256 + threadIdx.x;
    atomicAdd(&counts[dst[i]], 1);
}

__global__ __launch_bounds__(256) void scan_kernel(const int* __restrict__ counts,
                                                   int* __restrict__ rowptr)
{
    const int PER = (N_NODES + 255) / 256;     // 157
    const int tid = threadIdx.x;
    const int base = tid * PER;
    int s = 0;
    for (int i = 0; i < PER; ++i) {
        const int idx = base + i;
        if (idx < N_NODES) s += counts[idx];
    }
    __shared__ int sm[256];
    sm[tid] = s;
    __syncthreads();
    for (int off = 1; off < 256; off <<= 1) {
        int t = (tid >= off) ? sm[tid - off] : 0;
        __syncthreads();
        sm[tid] += t;
        __syncthreads();
    }
    const int incl = sm[tid];
    int run = incl - s;
    for (int i = 0; i < PER; ++i) {
        const int idx = base + i;
        if (idx < N_NODES) {
            rowptr[idx] = run;
            run += counts[idx];
        }
    }
    if (tid == 255) rowptr[N_NODES] = incl;
}

__global__ __launch_bounds__(256) void fill_kernel(const int* __restrict__ dst,
                                                   int* __restrict__ cursor,
                                                   int* __restrict__ eids)
{
    const int e = blockIdx.x * 256 + threadIdx.x;
    const int pos = atomicAdd(&cursor[dst[e]], 1);
    if (pos >= 0 && pos < N_EDGES) eids[pos] = e;
}

// ---------------------------------------------------------------------------
// Gather aggregation: one wave per dst node, register softmax, no atomics.
// ---------------------------------------------------------------------------
__global__ __launch_bounds__(256) void gather_kernel(const float* __restrict__ qkv,
                                                     const float* __restrict__ esc,
                                                     const int* __restrict__ src,
                                                     const int* __restrict__ rowptr,
                                                     const int* __restrict__ eids,
                                                     const float* __restrict__ triplet_h,
                                                     float* __restrict__ x)
{
    const int node = blockIdx.x * 4 + (threadIdx.x >> 6);
    const int lane = threadIdx.x & 63;
    const int h    = lane >> 3;
    int beg = rowptr[node];
    int end = rowptr[node + 1];
    beg = max(0, min(beg, N_EDGES));
    end = max(beg, min(end, N_EDGES));

    float dsum = 0.0f;
    for (int j = beg; j < end; ++j) {
        const int e = eids[j];
        dsum += esc[(size_t)e * H + h];
    }
    const float inv = 1.0f / dsum;

    float4 acc = {0.0f, 0.0f, 0.0f, 0.0f};
    for (int j = beg; j < end; ++j) {
        const int e  = eids[j];
        const int se = src[e];
        const float w = esc[(size_t)e * H + h] * inv;
        const float4 v = *reinterpret_cast<const float4*>(
            qkv + (size_t)se * D3 + 512 + lane * 4);
        acc.x += v.x * w;
        acc.y += v.y * w;
        acc.z += v.z * w;
        acc.w += v.w * w;
    }
    const float4 th = *reinterpret_cast<const float4*>(
        triplet_h + (size_t)node * D + lane * 4);
    float4 o;
    o.x = th.x + acc.x;
    o.y = th.y + acc.y;
    o.z = th.z + acc.z;
    o.w = th.w + acc.w;
    *reinterpret_cast<float4*>(x + (size_t)node * D + lane * 4) = o;
}

// ---------------------------------------------------------------------------
extern "C" void kernel_launch(void* const* d_in, const int* in_sizes, int n_in,
                              void* d_out, int out_size, void* d_ws, size_t ws_size,
                              hipStream_t stream)
{
    const float* triplet_h = (const float*)d_in[0];
    const int*   src       = (const int*)d_in[1];
    const int*   dst       = (const int*)d_in[2];
    const float* Wqkv      = (const float*)d_in[3];
    const float* bqkv      = (const float*)d_in[4];
    const float* ln_attn_g = (const float*)d_in[5];
    const float* ln_attn_b = (const float*)d_in[6];
    const float* ln_res_g  = (const float*)d_in[7];
    const float* ln_res_b  = (const float*)d_in[8];
    const float* W_in      = (const float*)d_in[9];
    const float* b_in      = (const float*)d_in[10];
    const float* W_out     = (const float*)d_in[11];
    const float* b_out     = (const float*)d_in[12];
    float* out = (float*)d_out;

    // Workspace (~209 MB < proven 245.76 MB ceiling):
    char* w = (char*)d_ws;
    float*          bufA   = (float*)w;          w += (size_t)N_NODES * D3 * sizeof(float);   // qkv fp32 OR a1 bf16
    unsigned short* h_xn   = (unsigned short*)w; w += (size_t)M_PAD * D * sizeof(unsigned short); // h/xn bf16
    float*          x      = (float*)w;          w += (size_t)N_NODES * D * sizeof(float);
    float*          esc    = (float*)w;          w += (size_t)N_EDGES * H * sizeof(float);
    unsigned short* Wqkv_pk= (unsigned short*)w; w += (size_t)D * D3 * sizeof(unsigned short);
    unsigned short* Win_pk = (unsigned short*)w; w += (size_t)D * DFF * sizeof(unsigned short);
    unsigned short* Wout_pk= (unsigned short*)w; w += (size_t)DFF * D * sizeof(unsigned short);
    int* counts = (int*)w;  w += (size_t)N_NODES * sizeof(int);
    int* rowptr = (int*)w;  w += (size_t)(N_NODES + 1) * sizeof(int);
    int* cursor = (int*)w;  w += (size_t)N_NODES * sizeof(int);
    int* eids   = (int*)w;  w += (size_t)N_EDGES * sizeof(int);

    float* qkv = bufA;                           // [40000][768] fp32, dead after gather
    unsigned short* a1 = (unsigned short*)bufA;  // [M_PAD][1024] bf16, live FFN only

    // ---- CSR build ----
    hipMemsetAsync(counts, 0, (size_t)N_NODES * sizeof(int), stream);
    hist_kernel<<<N_EDGES / 256, 256, 0, stream>>>(dst, counts);
    scan_kernel<<<1, 256, 0, stream>>>(counts, rowptr);
    hipMemcpyAsync(cursor, rowptr, (size_t)N_NODES * sizeof(int),
                   hipMemcpyDeviceToDevice, stream);
    fill_kernel<<<N_EDGES / 256, 256, 0, stream>>>(dst, cursor, eids);

    // ---- weight packing (bf16 fragment-order) ----
    pack_w_kernel<D,  D3 ><<<(D * D3 / 8) / 256, 256, 0, stream>>>(Wqkv, Wqkv_pk);
    pack_w_kernel<D,  DFF><<<(D * DFF / 8) / 256, 256, 0, stream>>>(W_in, Win_pk);
    pack_w_kernel<DFF, D ><<<(DFF * D / 8) / 256, 256, 0, stream>>>(W_out, Wout_pk);

    // h/xn pad rows (rows 40000..40063) -> zero, persists all call
    hipMemsetAsync(h_xn + (size_t)N_NODES * D, 0,
                   (size_t)(M_PAD - N_NODES) * D * sizeof(unsigned short), stream);

    // ---- main pipeline ----
    ln_bf_kernel<<<N_NODES / 4, 256, 0, stream>>>(triplet_h, ln_attn_g, ln_attn_b, h_xn);
    mfma_gemm_kernel<0, D, D3><<<dim3(D3 / 128, M_PAD / 128), 256, 0, stream>>>(
        h_xn, Wqkv_pk, bqkv, qkv, nullptr);
    score_kernel<<<N_EDGES / 4, 256, 0, stream>>>(qkv, src, dst, esc);
    gather_kernel<<<N_NODES / 4, 256, 0, stream>>>(qkv, esc, src, rowptr, eids,
                                                   triplet_h, x);
    ln_bf_kernel<<<N_NODES / 4, 256, 0, stream>>>(x, ln_res_g, ln_res_b, h_xn);
    // qkv dead; zero a1 pad rows (aliases old qkv bytes) before FFN GEMMs
    hipMemsetAsync(a1 + (size_t)N_NODES * DFF, 0,
                   (size_t)(M_PAD - N_NODES) * DFF * sizeof(unsigned short), stream);
    mfma_gemm_kernel<1, D, DFF><<<dim3(DFF / 128, M_PAD / 128), 256, 0, stream>>>(
        h_xn, Win_pk, b_in, a1, nullptr);
    mfma_gemm_kernel<2, DFF, D><<<dim3(D / 128, M_PAD / 128), 256, 0, stream>>>(
        a1, Wout_pk, b_out, out, x);

    (void)in_sizes; (void)n_in; (void)out_size; (void)ws_size;
}

// Round 5
// 587.059 us; speedup vs baseline: 5.4827x; 1.4287x over previous
//
#include <hip/hip_runtime.h>
#include <math.h>

#define N_NODES 40000
#define M_PAD   40064      // 313 * 128
#define N_EDGES 640000
#define D       256
#define H       8
#define DFF     1024
#define D3      768
#define ATT_SCALE 0.0625f  // 256^-0.5
#define LN_EPS  1e-5f

typedef __attribute__((ext_vector_type(8))) short short8;
typedef __attribute__((ext_vector_type(4))) float f32x4;

__device__ __forceinline__ unsigned short f2bf(float f) {
    unsigned int u = __builtin_bit_cast(unsigned int, f);
    u = (u + 0x7FFF + ((u >> 16) & 1)) >> 16;   // RTNE
    return (unsigned short)u;
}
__device__ __forceinline__ float bf2f(unsigned short u) {
    return __builtin_bit_cast(float, (unsigned int)u << 16);
}

// ---------------------------------------------------------------------------
// LayerNorm -> bf16 row-major output. One wave per row. (LN1 only)
// ---------------------------------------------------------------------------
__global__ __launch_bounds__(256) void ln_bf_kernel(const float* __restrict__ in,
                                                    const float* __restrict__ g,
                                                    const float* __restrict__ b,
                                                    unsigned short* __restrict__ out)
{
    const int row  = blockIdx.x * 4 + (threadIdx.x >> 6);
    const int lane = threadIdx.x & 63;
    const float4 v = *reinterpret_cast<const float4*>(in + (size_t)row * D + lane * 4);
    float s  = v.x + v.y + v.z + v.w;
    float s2 = v.x * v.x + v.y * v.y + v.z * v.z + v.w * v.w;
#pragma unroll
    for (int o = 32; o > 0; o >>= 1) {
        s  += __shfl_xor(s,  o, 64);
        s2 += __shfl_xor(s2, o, 64);
    }
    const float mu  = s * (1.0f / D);
    const float var = s2 * (1.0f / D) - mu * mu;
    const float rs  = rsqrtf(var + LN_EPS);
    const float4 gg = *reinterpret_cast<const float4*>(g + lane * 4);
    const float4 bb = *reinterpret_cast<const float4*>(b + lane * 4);
    ushort4 o4;
    o4.x = f2bf((v.x - mu) * rs * gg.x + bb.x);
    o4.y = f2bf((v.y - mu) * rs * gg.y + bb.y);
    o4.z = f2bf((v.z - mu) * rs * gg.z + bb.z);
    o4.w = f2bf((v.w - mu) * rs * gg.w + bb.w);
    *reinterpret_cast<ushort4*>(out + (size_t)row * D + lane * 4) = o4;
}

// ---------------------------------------------------------------------------
// Weight pack: W[K][N] fp32 -> bf16 packed [N/16][K/8][16][8].
// ---------------------------------------------------------------------------
template <int K, int N>
__global__ __launch_bounds__(256) void pack_w_kernel(const float* __restrict__ W,
                                                     unsigned short* __restrict__ Wpk)
{
    const int idx = blockIdx.x * 256 + threadIdx.x;   // [N/16][K/8][16]
    const int ni  = idx & 15;
    const int kc  = (idx >> 4) % (K / 8);
    const int nt  = idx / (16 * (K / 8));
    const int n   = nt * 16 + ni;
    unsigned short o[8];
#pragma unroll
    for (int i = 0; i < 8; ++i)
        o[i] = f2bf(W[(size_t)(kc * 8 + i) * N + n]);
    *reinterpret_cast<short8*>(Wpk + (size_t)idx * 8) = *reinterpret_cast<short8*>(o);
}

// ---------------------------------------------------------------------------
// bf16 MFMA GEMM. Block 256 thr = 4 waves; 128x128 tile; BK=32.
// EPI 0: bf16 C, scale cols<256 by ATT_SCALE (qkv)
// EPI 1: bf16 C with exact gelu (a1)
// EPI 2: fp32 C += Xadd (final residual)
// ---------------------------------------------------------------------------
template <int EPI, int K, int N>
__global__ __launch_bounds__(256) void mfma_gemm_kernel(const unsigned short* __restrict__ A,
                                                        const unsigned short* __restrict__ Bpk,
                                                        const float* __restrict__ bias,
                                                        void* __restrict__ Cout,
                                                        const float* __restrict__ Xadd)
{
    __shared__ unsigned short As[4096];   // [mt8][kc4][mi16][ki8] = 8 KB
    __shared__ unsigned short Bs[4096];   // [nt8][kc4][ni16][ki8] = 8 KB

    const int tid  = threadIdx.x;
    const int wave = tid >> 6;
    const int lane = tid & 63;
    const int row0 = blockIdx.y * 128;
    const int col0 = blockIdx.x * 128;
    const int wm   = (wave >> 1) * 64;
    const int wn   = (wave & 1) * 64;

    f32x4 acc[4][4] = {};

    const int lq  = (lane >> 4);
    const int lm  = (lane & 15);
    const int fragoff = lq * 128 + lm * 8;

    for (int k0 = 0; k0 < K; k0 += 32) {
#pragma unroll
        for (int p = 0; p < 2; ++p) {
            const int q  = p * 256 + tid;
            const int c  = q & 3;
            const int mi = (q >> 2) & 15;
            const int mt = q >> 6;
            const short8 v = *reinterpret_cast<const short8*>(
                A + (size_t)(row0 + mt * 16 + mi) * K + k0 + c * 8);
            *reinterpret_cast<short8*>(&As[mt * 512 + c * 128 + mi * 8]) = v;
        }
#pragma unroll
        for (int p = 0; p < 2; ++p) {
            const int q   = p * 256 + tid;
            const int nt  = q >> 6;
            const int rem = q & 63;
            const short8 v = *reinterpret_cast<const short8*>(
                Bpk + ((size_t)(col0 / 16 + nt) * (K / 8) + k0 / 8) * 128 + rem * 8);
            *reinterpret_cast<short8*>(&Bs[q * 8]) = v;
        }
        __syncthreads();

        short8 af[4], bf[4];
#pragma unroll
        for (int i = 0; i < 4; ++i) {
            af[i] = *reinterpret_cast<const short8*>(&As[(wm / 16 + i) * 512 + fragoff]);
            bf[i] = *reinterpret_cast<const short8*>(&Bs[(wn / 16 + i) * 512 + fragoff]);
        }
#pragma unroll
        for (int i = 0; i < 4; ++i)
#pragma unroll
            for (int j = 0; j < 4; ++j)
                acc[i][j] = __builtin_amdgcn_mfma_f32_16x16x32_bf16(af[i], bf[j], acc[i][j], 0, 0, 0);
        __syncthreads();
    }

    // C/D layout: col=lane&15, row=(lane>>4)*4+t
#pragma unroll
    for (int j = 0; j < 4; ++j) {
        const int col = col0 + wn + j * 16 + (lane & 15);
        const float bz = bias[col];
#pragma unroll
        for (int i = 0; i < 4; ++i) {
#pragma unroll
            for (int t = 0; t < 4; ++t) {
                const int r = row0 + wm + i * 16 + (lane >> 4) * 4 + t;
                if (r < N_NODES) {
                    float o = acc[i][j][t] + bz;
                    if (EPI == 0) {
                        if (col < 256) o *= ATT_SCALE;
                        ((unsigned short*)Cout)[(size_t)r * N + col] = f2bf(o);
                    } else if (EPI == 1) {
                        o = 0.5f * o * (1.0f + erff(o * 0.70710678118654752f));
                        ((unsigned short*)Cout)[(size_t)r * N + col] = f2bf(o);
                    } else {
                        o += Xadd[(size_t)r * N + col];
                        ((float*)Cout)[(size_t)r * N + col] = o;
                    }
                }
            }
        }
    }
}

// ---------------------------------------------------------------------------
// CSR build: histogram -> chunked single-block scan (256 thr) -> fill
// fill writes src_sorted directly (no eids indirection in the hot loop).
// ---------------------------------------------------------------------------
__global__ __launch_bounds__(256) void hist_kernel(const int* __restrict__ dst,
                                                   int* __restrict__ counts)
{
    const int i = blockIdx.x * 256 + threadIdx.x;
    atomicAdd(&counts[dst[i]], 1);
}

__global__ __launch_bounds__(256) void scan_kernel(const int* __restrict__ counts,
                                                   int* __restrict__ rowptr)
{
    const int PER = (N_NODES + 255) / 256;     // 157
    const int tid = threadIdx.x;
    const int base = tid * PER;
    int s = 0;
    for (int i = 0; i < PER; ++i) {
        const int idx = base + i;
        if (idx < N_NODES) s += counts[idx];
    }
    __shared__ int sm[256];
    sm[tid] = s;
    __syncthreads();
    for (int off = 1; off < 256; off <<= 1) {
        int t = (tid >= off) ? sm[tid - off] : 0;
        __syncthreads();
        sm[tid] += t;
        __syncthreads();
    }
    const int incl = sm[tid];
    int run = incl - s;
    for (int i = 0; i < PER; ++i) {
        const int idx = base + i;
        if (idx < N_NODES) {
            rowptr[idx] = run;
            run += counts[idx];
        }
    }
    if (tid == 255) rowptr[N_NODES] = incl;
}

__global__ __launch_bounds__(256) void fill_kernel(const int* __restrict__ src,
                                                   const int* __restrict__ dst,
                                                   int* __restrict__ cursor,
                                                   int* __restrict__ srcs)
{
    const int e = blockIdx.x * 256 + threadIdx.x;
    const int pos = atomicAdd(&cursor[dst[e]], 1);
    if (pos >= 0 && pos < N_EDGES) srcs[pos] = src[e];
}

// ---------------------------------------------------------------------------
// Fused attention: score + single-pass softmax + aggregate + residual + LN2.
// One wave per dst node. Lane l owns dims l*4..l*4+3 (head = l>>3).
// qkv is bf16 [N][768], q pre-scaled by ATT_SCALE.
// Outputs: x = triplet_h + agg (fp32), xn = LN(x) (bf16).
// ---------------------------------------------------------------------------
__global__ __launch_bounds__(256) void fused_attn_kernel(const unsigned short* __restrict__ qkv,
                                                         const int* __restrict__ srcs,
                                                         const int* __restrict__ rowptr,
                                                         const float* __restrict__ triplet_h,
                                                         const float* __restrict__ g,
                                                         const float* __restrict__ b,
                                                         float* __restrict__ x,
                                                         unsigned short* __restrict__ xn)
{
    const int node = blockIdx.x * 4 + (threadIdx.x >> 6);
    const int lane = threadIdx.x & 63;
    int beg = rowptr[node];
    int end = rowptr[node + 1];
    beg = max(0, min(beg, N_EDGES));
    end = max(beg, min(end, N_EDGES));

    // k[dst] fragment (4 dims), once per node
    const ushort4 ku = *reinterpret_cast<const ushort4*>(
        qkv + (size_t)node * D3 + 256 + lane * 4);
    const float k0 = bf2f(ku.x), k1 = bf2f(ku.y), k2 = bf2f(ku.z), k3 = bf2f(ku.w);

    float dsum = 0.0f;
    float4 acc = {0.0f, 0.0f, 0.0f, 0.0f};

    for (int j = beg; j < end; ++j) {
        const int se = srcs[j];
        const ushort4 qu = *reinterpret_cast<const ushort4*>(
            qkv + (size_t)se * D3 + lane * 4);
        float p = bf2f(qu.x) * k0 + bf2f(qu.y) * k1 + bf2f(qu.z) * k2 + bf2f(qu.w) * k3;
        p += __shfl_xor(p, 1, 64);
        p += __shfl_xor(p, 2, 64);
        p += __shfl_xor(p, 4, 64);           // full per-head dot in all 8 lanes
        const float wgt = expf(p);
        const ushort4 vu = *reinterpret_cast<const ushort4*>(
            qkv + (size_t)se * D3 + 512 + lane * 4);
        acc.x += wgt * bf2f(vu.x);
        acc.y += wgt * bf2f(vu.y);
        acc.z += wgt * bf2f(vu.z);
        acc.w += wgt * bf2f(vu.w);
        dsum += wgt;
    }
    const float inv = (end > beg) ? 1.0f / dsum : 0.0f;

    const float4 th = *reinterpret_cast<const float4*>(
        triplet_h + (size_t)node * D + lane * 4);
    float4 xv;
    xv.x = th.x + acc.x * inv;
    xv.y = th.y + acc.y * inv;
    xv.z = th.z + acc.z * inv;
    xv.w = th.w + acc.w * inv;
    *reinterpret_cast<float4*>(x + (size_t)node * D + lane * 4) = xv;

    // LN2 across the wave
    float s  = xv.x + xv.y + xv.z + xv.w;
    float s2 = xv.x * xv.x + xv.y * xv.y + xv.z * xv.z + xv.w * xv.w;
#pragma unroll
    for (int o = 32; o > 0; o >>= 1) {
        s  += __shfl_xor(s,  o, 64);
        s2 += __shfl_xor(s2, o, 64);
    }
    const float mu  = s * (1.0f / D);
    const float var = s2 * (1.0f / D) - mu * mu;
    const float rs  = rsqrtf(var + LN_EPS);
    const float4 gg = *reinterpret_cast<const float4*>(g + lane * 4);
    const float4 bb = *reinterpret_cast<const float4*>(b + lane * 4);
    ushort4 o4;
    o4.x = f2bf((xv.x - mu) * rs * gg.x + bb.x);
    o4.y = f2bf((xv.y - mu) * rs * gg.y + bb.y);
    o4.z = f2bf((xv.z - mu) * rs * gg.z + bb.z);
    o4.w = f2bf((xv.w - mu) * rs * gg.w + bb.w);
    *reinterpret_cast<ushort4*>(xn + (size_t)node * D + lane * 4) = o4;
}

// ---------------------------------------------------------------------------
extern "C" void kernel_launch(void* const* d_in, const int* in_sizes, int n_in,
                              void* d_out, int out_size, void* d_ws, size_t ws_size,
                              hipStream_t stream)
{
    const float* triplet_h = (const float*)d_in[0];
    const int*   src       = (const int*)d_in[1];
    const int*   dst       = (const int*)d_in[2];
    const float* Wqkv      = (const float*)d_in[3];
    const float* bqkv      = (const float*)d_in[4];
    const float* ln_attn_g = (const float*)d_in[5];
    const float* ln_attn_b = (const float*)d_in[6];
    const float* ln_res_g  = (const float*)d_in[7];
    const float* ln_res_b  = (const float*)d_in[8];
    const float* W_in      = (const float*)d_in[9];
    const float* b_in      = (const float*)d_in[10];
    const float* W_out     = (const float*)d_in[11];
    const float* b_out     = (const float*)d_in[12];
    float* out = (float*)d_out;

    // Workspace (~150 MB, well under proven 245.76 MB ceiling):
    char* w = (char*)d_ws;
    unsigned short* bufA = (unsigned short*)w;   // qkv bf16 [N][768] OR a1 bf16 [M_PAD][1024]
    w += (size_t)M_PAD * DFF * sizeof(unsigned short);                    // 82.05 MB
    unsigned short* h_xn = (unsigned short*)w;  w += (size_t)M_PAD * D * sizeof(unsigned short);
    float*          x    = (float*)w;           w += (size_t)N_NODES * D * sizeof(float);
    unsigned short* Wqkv_pk = (unsigned short*)w; w += (size_t)D * D3 * sizeof(unsigned short);
    unsigned short* Win_pk  = (unsigned short*)w; w += (size_t)D * DFF * sizeof(unsigned short);
    unsigned short* Wout_pk = (unsigned short*)w; w += (size_t)DFF * D * sizeof(unsigned short);
    int* counts = (int*)w;  w += (size_t)N_NODES * sizeof(int);
    int* rowptr = (int*)w;  w += (size_t)(N_NODES + 1) * sizeof(int);
    int* cursor = (int*)w;  w += (size_t)N_NODES * sizeof(int);
    int* srcs   = (int*)w;  w += (size_t)N_EDGES * sizeof(int);

    unsigned short* qkv = bufA;  // [40000][768] bf16, dead after fused_attn
    unsigned short* a1  = bufA;  // [M_PAD][1024] bf16, live FFN only

    // ---- CSR build ----
    hipMemsetAsync(counts, 0, (size_t)N_NODES * sizeof(int), stream);
    hist_kernel<<<N_EDGES / 256, 256, 0, stream>>>(dst, counts);
    scan_kernel<<<1, 256, 0, stream>>>(counts, rowptr);
    hipMemcpyAsync(cursor, rowptr, (size_t)N_NODES * sizeof(int),
                   hipMemcpyDeviceToDevice, stream);
    fill_kernel<<<N_EDGES / 256, 256, 0, stream>>>(src, dst, cursor, srcs);

    // ---- weight packing ----
    pack_w_kernel<D,  D3 ><<<(D * D3 / 8) / 256, 256, 0, stream>>>(Wqkv, Wqkv_pk);
    pack_w_kernel<D,  DFF><<<(D * DFF / 8) / 256, 256, 0, stream>>>(W_in, Win_pk);
    pack_w_kernel<DFF, D ><<<(DFF * D / 8) / 256, 256, 0, stream>>>(W_out, Wout_pk);

    // h/xn pad rows -> zero (persists whole call)
    hipMemsetAsync(h_xn + (size_t)N_NODES * D, 0,
                   (size_t)(M_PAD - N_NODES) * D * sizeof(unsigned short), stream);

    // ---- main pipeline ----
    ln_bf_kernel<<<N_NODES / 4, 256, 0, stream>>>(triplet_h, ln_attn_g, ln_attn_b, h_xn);
    mfma_gemm_kernel<0, D, D3><<<dim3(D3 / 128, M_PAD / 128), 256, 0, stream>>>(
        h_xn, Wqkv_pk, bqkv, qkv, nullptr);
    fused_attn_kernel<<<N_NODES / 4, 256, 0, stream>>>(qkv, srcs, rowptr, triplet_h,
                                                       ln_res_g, ln_res_b, x, h_xn);
    // qkv dead; zero a1 pad rows (aliases old qkv bytes) before FFN GEMMs
    hipMemsetAsync(a1 + (size_t)N_NODES * DFF, 0,
                   (size_t)(M_PAD - N_NODES) * DFF * sizeof(unsigned short), stream);
    mfma_gemm_kernel<1, D, DFF><<<dim3(DFF / 128, M_PAD / 128), 256, 0, stream>>>(
        h_xn, Win_pk, b_in, a1, nullptr);
    mfma_gemm_kernel<2, DFF, D><<<dim3(D / 128, M_PAD / 128), 256, 0, stream>>>(
        a1, Wout_pk, b_out, out, x);

    (void)in_sizes; (void)n_in; (void)out_size; (void)ws_size;
}

// Round 6
// 575.573 us; speedup vs baseline: 5.5921x; 1.0200x over previous
//
#include <hip/hip_runtime.h>
#include <math.h>

#define N_NODES 40000
#define M_PAD   40064      // 313 * 128
#define N_EDGES 640000
#define D       256
#define H       8
#define DFF     1024
#define D3      768
#define ATT_SCALE 0.0625f  // 256^-0.5
#define LN_EPS  1e-5f

typedef __attribute__((ext_vector_type(8))) short short8;
typedef __attribute__((ext_vector_type(4))) float f32x4;

__device__ __forceinline__ unsigned short f2bf(float f) {
    unsigned int u = __builtin_bit_cast(unsigned int, f);
    u = (u + 0x7FFF + ((u >> 16) & 1)) >> 16;   // RTNE
    return (unsigned short)u;
}
__device__ __forceinline__ float bf2f(unsigned short u) {
    return __builtin_bit_cast(float, (unsigned int)u << 16);
}

#define GLOAD_LDS16(g, l) \
    __builtin_amdgcn_global_load_lds((const __attribute__((address_space(1))) void*)(g), \
                                     (__attribute__((address_space(3))) void*)(l), 16, 0, 0)

// ---------------------------------------------------------------------------
// LayerNorm -> bf16 output in MFMA A-fragment order [M/16][D/8][16][8].
// One wave per row; lane covers cols lane*4..lane*4+3.
// ---------------------------------------------------------------------------
__global__ __launch_bounds__(256) void ln_bf_kernel(const float* __restrict__ in,
                                                    const float* __restrict__ g,
                                                    const float* __restrict__ b,
                                                    unsigned short* __restrict__ out)
{
    const int row  = blockIdx.x * 4 + (threadIdx.x >> 6);
    const int lane = threadIdx.x & 63;
    const float4 v = *reinterpret_cast<const float4*>(in + (size_t)row * D + lane * 4);
    float s  = v.x + v.y + v.z + v.w;
    float s2 = v.x * v.x + v.y * v.y + v.z * v.z + v.w * v.w;
#pragma unroll
    for (int o = 32; o > 0; o >>= 1) {
        s  += __shfl_xor(s,  o, 64);
        s2 += __shfl_xor(s2, o, 64);
    }
    const float mu  = s * (1.0f / D);
    const float var = s2 * (1.0f / D) - mu * mu;
    const float rs  = rsqrtf(var + LN_EPS);
    const float4 gg = *reinterpret_cast<const float4*>(g + lane * 4);
    const float4 bb = *reinterpret_cast<const float4*>(b + lane * 4);
    ushort4 o4;
    o4.x = f2bf((v.x - mu) * rs * gg.x + bb.x);
    o4.y = f2bf((v.y - mu) * rs * gg.y + bb.y);
    o4.z = f2bf((v.z - mu) * rs * gg.z + bb.z);
    o4.w = f2bf((v.w - mu) * rs * gg.w + bb.w);
    // fragment order: mt=row>>4, kc=lane>>1, mi=row&15, ki=(lane&1)*4
    const size_t off = (((size_t)(row >> 4) * (D / 8) + (lane >> 1)) * 16 + (row & 15)) * 8
                       + (lane & 1) * 4;
    *reinterpret_cast<ushort4*>(out + off) = o4;
}

// ---------------------------------------------------------------------------
// Weight pack: W[K][N] fp32 -> bf16 packed [N/16][K/8][16][8].
// ---------------------------------------------------------------------------
template <int K, int N>
__global__ __launch_bounds__(256) void pack_w_kernel(const float* __restrict__ W,
                                                     unsigned short* __restrict__ Wpk)
{
    const int idx = blockIdx.x * 256 + threadIdx.x;   // [N/16][K/8][16]
    const int ni  = idx & 15;
    const int kc  = (idx >> 4) % (K / 8);
    const int nt  = idx / (16 * (K / 8));
    const int n   = nt * 16 + ni;
    unsigned short o[8];
#pragma unroll
    for (int i = 0; i < 8; ++i)
        o[i] = f2bf(W[(size_t)(kc * 8 + i) * N + n]);
    *reinterpret_cast<short8*>(Wpk + (size_t)idx * 8) = *reinterpret_cast<short8*>(o);
}

// ---------------------------------------------------------------------------
// bf16 MFMA GEMM, both operands pre-packed fragment order.
// A: [M/16][K/8][16][8]   B: [N/16][K/8][16][8]
// Block 256 thr = 4 waves; 128x128 tile; BK=32; staging via global_load_lds.
// EPI 0: bf16 C row-major, scale cols<256 by ATT_SCALE (qkv)
// EPI 1: bf16 C in fragment order [M/16][N/8][16][8] with exact gelu (a1)
// EPI 2: fp32 C row-major += Xadd (final residual)
// ---------------------------------------------------------------------------
template <int EPI, int K, int N>
__global__ __launch_bounds__(256) void mfma_gemm_kernel(const unsigned short* __restrict__ A,
                                                        const unsigned short* __restrict__ Bpk,
                                                        const float* __restrict__ bias,
                                                        void* __restrict__ Cout,
                                                        const float* __restrict__ Xadd)
{
    __shared__ unsigned short As[4096];   // [mt8][kc4][mi16][ki8] = 8 KB
    __shared__ unsigned short Bs[4096];   // [nt8][kc4][ni16][ki8] = 8 KB

    const int tid  = threadIdx.x;
    const int wave = tid >> 6;
    const int lane = tid & 63;
    const int row0 = blockIdx.y * 128;
    const int col0 = blockIdx.x * 128;
    const int wm   = (wave >> 1) * 64;
    const int wn   = (wave & 1) * 64;

    f32x4 acc[4][4] = {};

    const int fragoff = (lane >> 4) * 128 + (lane & 15) * 8;

    for (int k0 = 0; k0 < K; k0 += 32) {
        const int kq = k0 >> 3;   // k-chunk index (K/8 units)
        // Each wave DMAs 2 A-chunks + 2 B-chunks of 1 KB (64 lanes x 16 B).
#pragma unroll
        for (int c = 0; c < 2; ++c) {
            const int mt = wave * 2 + c;                 // 0..7
            const unsigned short* gA =
                A + ((size_t)(row0 / 16 + mt) * (K / 8) + kq) * 128 + lane * 8;
            GLOAD_LDS16(gA, &As[mt * 512]);
            const unsigned short* gB =
                Bpk + ((size_t)(col0 / 16 + mt) * (K / 8) + kq) * 128 + lane * 8;
            GLOAD_LDS16(gB, &Bs[mt * 512]);
        }
        __syncthreads();

        short8 af[4], bf[4];
#pragma unroll
        for (int i = 0; i < 4; ++i) {
            af[i] = *reinterpret_cast<const short8*>(&As[(wm / 16 + i) * 512 + fragoff]);
            bf[i] = *reinterpret_cast<const short8*>(&Bs[(wn / 16 + i) * 512 + fragoff]);
        }
#pragma unroll
        for (int i = 0; i < 4; ++i)
#pragma unroll
            for (int j = 0; j < 4; ++j)
                acc[i][j] = __builtin_amdgcn_mfma_f32_16x16x32_bf16(af[i], bf[j], acc[i][j], 0, 0, 0);
        __syncthreads();
    }

    // C/D layout: col=lane&15, row=(lane>>4)*4+t
#pragma unroll
    for (int j = 0; j < 4; ++j) {
        const int col = col0 + wn + j * 16 + (lane & 15);
        const float bz = bias[col];
#pragma unroll
        for (int i = 0; i < 4; ++i) {
#pragma unroll
            for (int t = 0; t < 4; ++t) {
                const int r = row0 + wm + i * 16 + (lane >> 4) * 4 + t;
                if (r < N_NODES) {
                    float o = acc[i][j][t] + bz;
                    if (EPI == 0) {
                        if (col < 256) o *= ATT_SCALE;
                        ((unsigned short*)Cout)[(size_t)r * N + col] = f2bf(o);
                    } else if (EPI == 1) {
                        o = 0.5f * o * (1.0f + erff(o * 0.70710678118654752f));
                        // fragment order for next GEMM's A (K=N here)
                        const size_t off = (((size_t)(r >> 4) * (N / 8) + (col >> 3)) * 16
                                            + (r & 15)) * 8 + (col & 7);
                        ((unsigned short*)Cout)[off] = f2bf(o);
                    } else {
                        o += Xadd[(size_t)r * N + col];
                        ((float*)Cout)[(size_t)r * N + col] = o;
                    }
                }
            }
        }
    }
}

// ---------------------------------------------------------------------------
// CSR build: histogram -> chunked single-block scan (256 thr) -> fill
// ---------------------------------------------------------------------------
__global__ __launch_bounds__(256) void hist_kernel(const int* __restrict__ dst,
                                                   int* __restrict__ counts)
{
    const int i = blockIdx.x * 256 + threadIdx.x;
    atomicAdd(&counts[dst[i]], 1);
}

__global__ __launch_bounds__(256) void scan_kernel(const int* __restrict__ counts,
                                                   int* __restrict__ rowptr)
{
    const int PER = (N_NODES + 255) / 256;     // 157
    const int tid = threadIdx.x;
    const int base = tid * PER;
    int s = 0;
    for (int i = 0; i < PER; ++i) {
        const int idx = base + i;
        if (idx < N_NODES) s += counts[idx];
    }
    __shared__ int sm[256];
    sm[tid] = s;
    __syncthreads();
    for (int off = 1; off < 256; off <<= 1) {
        int t = (tid >= off) ? sm[tid - off] : 0;
        __syncthreads();
        sm[tid] += t;
        __syncthreads();
    }
    const int incl = sm[tid];
    int run = incl - s;
    for (int i = 0; i < PER; ++i) {
        const int idx = base + i;
        if (idx < N_NODES) {
            rowptr[idx] = run;
            run += counts[idx];
        }
    }
    if (tid == 255) rowptr[N_NODES] = incl;
}

__global__ __launch_bounds__(256) void fill_kernel(const int* __restrict__ src,
                                                   const int* __restrict__ dst,
                                                   int* __restrict__ cursor,
                                                   int* __restrict__ srcs)
{
    const int e = blockIdx.x * 256 + threadIdx.x;
    const int pos = atomicAdd(&cursor[dst[e]], 1);
    if (pos >= 0 && pos < N_EDGES) srcs[pos] = src[e];
}

// ---------------------------------------------------------------------------
// Fused attention: score + single-pass softmax + aggregate + residual + LN2.
// One wave per dst node; 2-edge ILP unroll. qkv bf16 row-major, q pre-scaled.
// Outputs: x fp32 row-major, xn bf16 in fragment order.
// ---------------------------------------------------------------------------
__global__ __launch_bounds__(256) void fused_attn_kernel(const unsigned short* __restrict__ qkv,
                                                         const int* __restrict__ srcs,
                                                         const int* __restrict__ rowptr,
                                                         const float* __restrict__ triplet_h,
                                                         const float* __restrict__ g,
                                                         const float* __restrict__ b,
                                                         float* __restrict__ x,
                                                         unsigned short* __restrict__ xn)
{
    const int node = blockIdx.x * 4 + (threadIdx.x >> 6);
    const int lane = threadIdx.x & 63;
    int beg = rowptr[node];
    int end = rowptr[node + 1];
    beg = max(0, min(beg, N_EDGES));
    end = max(beg, min(end, N_EDGES));

    const ushort4 ku = *reinterpret_cast<const ushort4*>(
        qkv + (size_t)node * D3 + 256 + lane * 4);
    const float k0 = bf2f(ku.x), k1 = bf2f(ku.y), k2 = bf2f(ku.z), k3 = bf2f(ku.w);

    float dsum = 0.0f;
    float4 acc = {0.0f, 0.0f, 0.0f, 0.0f};

    int j = beg;
    for (; j + 2 <= end; j += 2) {
        const int s0 = srcs[j];
        const int s1 = srcs[j + 1];
        const ushort4 qa = *reinterpret_cast<const ushort4*>(qkv + (size_t)s0 * D3 + lane * 4);
        const ushort4 qb = *reinterpret_cast<const ushort4*>(qkv + (size_t)s1 * D3 + lane * 4);
        const ushort4 va = *reinterpret_cast<const ushort4*>(qkv + (size_t)s0 * D3 + 512 + lane * 4);
        const ushort4 vb = *reinterpret_cast<const ushort4*>(qkv + (size_t)s1 * D3 + 512 + lane * 4);
        float pa = bf2f(qa.x) * k0 + bf2f(qa.y) * k1 + bf2f(qa.z) * k2 + bf2f(qa.w) * k3;
        float pb = bf2f(qb.x) * k0 + bf2f(qb.y) * k1 + bf2f(qb.z) * k2 + bf2f(qb.w) * k3;
        pa += __shfl_xor(pa, 1, 64);  pb += __shfl_xor(pb, 1, 64);
        pa += __shfl_xor(pa, 2, 64);  pb += __shfl_xor(pb, 2, 64);
        pa += __shfl_xor(pa, 4, 64);  pb += __shfl_xor(pb, 4, 64);
        const float wa = expf(pa);
        const float wb = expf(pb);
        acc.x += wa * bf2f(va.x) + wb * bf2f(vb.x);
        acc.y += wa * bf2f(va.y) + wb * bf2f(vb.y);
        acc.z += wa * bf2f(va.z) + wb * bf2f(vb.z);
        acc.w += wa * bf2f(va.w) + wb * bf2f(vb.w);
        dsum += wa + wb;
    }
    if (j < end) {
        const int s0 = srcs[j];
        const ushort4 qa = *reinterpret_cast<const ushort4*>(qkv + (size_t)s0 * D3 + lane * 4);
        const ushort4 va = *reinterpret_cast<const ushort4*>(qkv + (size_t)s0 * D3 + 512 + lane * 4);
        float pa = bf2f(qa.x) * k0 + bf2f(qa.y) * k1 + bf2f(qa.z) * k2 + bf2f(qa.w) * k3;
        pa += __shfl_xor(pa, 1, 64);
        pa += __shfl_xor(pa, 2, 64);
        pa += __shfl_xor(pa, 4, 64);
        const float wa = expf(pa);
        acc.x += wa * bf2f(va.x);
        acc.y += wa * bf2f(va.y);
        acc.z += wa * bf2f(va.z);
        acc.w += wa * bf2f(va.w);
        dsum += wa;
    }
    const float inv = (end > beg) ? 1.0f / dsum : 0.0f;

    const float4 th = *reinterpret_cast<const float4*>(
        triplet_h + (size_t)node * D + lane * 4);
    float4 xv;
    xv.x = th.x + acc.x * inv;
    xv.y = th.y + acc.y * inv;
    xv.z = th.z + acc.z * inv;
    xv.w = th.w + acc.w * inv;
    *reinterpret_cast<float4*>(x + (size_t)node * D + lane * 4) = xv;

    // LN2 across the wave
    float s  = xv.x + xv.y + xv.z + xv.w;
    float s2 = xv.x * xv.x + xv.y * xv.y + xv.z * xv.z + xv.w * xv.w;
#pragma unroll
    for (int o = 32; o > 0; o >>= 1) {
        s  += __shfl_xor(s,  o, 64);
        s2 += __shfl_xor(s2, o, 64);
    }
    const float mu  = s * (1.0f / D);
    const float var = s2 * (1.0f / D) - mu * mu;
    const float rs  = rsqrtf(var + LN_EPS);
    const float4 gg = *reinterpret_cast<const float4*>(g + lane * 4);
    const float4 bb = *reinterpret_cast<const float4*>(b + lane * 4);
    ushort4 o4;
    o4.x = f2bf((xv.x - mu) * rs * gg.x + bb.x);
    o4.y = f2bf((xv.y - mu) * rs * gg.y + bb.y);
    o4.z = f2bf((xv.z - mu) * rs * gg.z + bb.z);
    o4.w = f2bf((xv.w - mu) * rs * gg.w + bb.w);
    const size_t off = (((size_t)(node >> 4) * (D / 8) + (lane >> 1)) * 16 + (node & 15)) * 8
                       + (lane & 1) * 4;
    *reinterpret_cast<ushort4*>(xn + off) = o4;
}

// ---------------------------------------------------------------------------
extern "C" void kernel_launch(void* const* d_in, const int* in_sizes, int n_in,
                              void* d_out, int out_size, void* d_ws, size_t ws_size,
                              hipStream_t stream)
{
    const float* triplet_h = (const float*)d_in[0];
    const int*   src       = (const int*)d_in[1];
    const int*   dst       = (const int*)d_in[2];
    const float* Wqkv      = (const float*)d_in[3];
    const float* bqkv      = (const float*)d_in[4];
    const float* ln_attn_g = (const float*)d_in[5];
    const float* ln_attn_b = (const float*)d_in[6];
    const float* ln_res_g  = (const float*)d_in[7];
    const float* ln_res_b  = (const float*)d_in[8];
    const float* W_in      = (const float*)d_in[9];
    const float* b_in      = (const float*)d_in[10];
    const float* W_out     = (const float*)d_in[11];
    const float* b_out     = (const float*)d_in[12];
    float* out = (float*)d_out;

    // Workspace (~150 MB, well under proven 245.76 MB ceiling):
    char* w = (char*)d_ws;
    unsigned short* bufA = (unsigned short*)w;   // qkv bf16 row-major OR a1 bf16 frag
    w += (size_t)M_PAD * DFF * sizeof(unsigned short);
    unsigned short* h_xn = (unsigned short*)w;  w += (size_t)M_PAD * D * sizeof(unsigned short);
    float*          x    = (float*)w;           w += (size_t)N_NODES * D * sizeof(float);
    unsigned short* Wqkv_pk = (unsigned short*)w; w += (size_t)D * D3 * sizeof(unsigned short);
    unsigned short* Win_pk  = (unsigned short*)w; w += (size_t)D * DFF * sizeof(unsigned short);
    unsigned short* Wout_pk = (unsigned short*)w; w += (size_t)DFF * D * sizeof(unsigned short);
    int* counts = (int*)w;  w += (size_t)N_NODES * sizeof(int);
    int* rowptr = (int*)w;  w += (size_t)(N_NODES + 1) * sizeof(int);
    int* cursor = (int*)w;  w += (size_t)N_NODES * sizeof(int);
    int* srcs   = (int*)w;  w += (size_t)N_EDGES * sizeof(int);

    unsigned short* qkv = bufA;  // [40000][768] bf16 row-major, dead after fused_attn
    unsigned short* a1  = bufA;  // [M_PAD/16][128][16][8] bf16 frag, live FFN only

    // ---- CSR build ----
    hipMemsetAsync(counts, 0, (size_t)N_NODES * sizeof(int), stream);
    hist_kernel<<<N_EDGES / 256, 256, 0, stream>>>(dst, counts);
    scan_kernel<<<1, 256, 0, stream>>>(counts, rowptr);
    hipMemcpyAsync(cursor, rowptr, (size_t)N_NODES * sizeof(int),
                   hipMemcpyDeviceToDevice, stream);
    fill_kernel<<<N_EDGES / 256, 256, 0, stream>>>(src, dst, cursor, srcs);

    // ---- weight packing ----
    pack_w_kernel<D,  D3 ><<<(D * D3 / 8) / 256, 256, 0, stream>>>(Wqkv, Wqkv_pk);
    pack_w_kernel<D,  DFF><<<(D * DFF / 8) / 256, 256, 0, stream>>>(W_in, Win_pk);
    pack_w_kernel<DFF, D ><<<(DFF * D / 8) / 256, 256, 0, stream>>>(W_out, Wout_pk);

    // h/xn pad rows (mt tiles 2500..2503) -> zero; frag region is byte-identical
    // to rows [40000,40064) x 256.
    hipMemsetAsync(h_xn + (size_t)N_NODES * D, 0,
                   (size_t)(M_PAD - N_NODES) * D * sizeof(unsigned short), stream);

    // ---- main pipeline ----
    ln_bf_kernel<<<N_NODES / 4, 256, 0, stream>>>(triplet_h, ln_attn_g, ln_attn_b, h_xn);
    mfma_gemm_kernel<0, D, D3><<<dim3(D3 / 128, M_PAD / 128), 256, 0, stream>>>(
        h_xn, Wqkv_pk, bqkv, qkv, nullptr);
    fused_attn_kernel<<<N_NODES / 4, 256, 0, stream>>>(qkv, srcs, rowptr, triplet_h,
                                                       ln_res_g, ln_res_b, x, h_xn);
    // qkv dead; zero a1 pad region (frag: byte-identical to rows [40000,40064) x 1024)
    hipMemsetAsync(a1 + (size_t)N_NODES * DFF, 0,
                   (size_t)(M_PAD - N_NODES) * DFF * sizeof(unsigned short), stream);
    mfma_gemm_kernel<1, D, DFF><<<dim3(DFF / 128, M_PAD / 128), 256, 0, stream>>>(
        h_xn, Win_pk, b_in, a1, nullptr);
    mfma_gemm_kernel<2, DFF, D><<<dim3(D / 128, M_PAD / 128), 256, 0, stream>>>(
        a1, Wout_pk, b_out, out, x);

    (void)in_sizes; (void)n_in; (void)out_size; (void)ws_size;
}